// Round 1
// baseline (32.975 us; speedup 1.0000x reference)
//
#include <hip/hip_runtime.h>

typedef float f32x4 __attribute__((ext_vector_type(4)));

constexpr int B_ = 8, L_ = 2048, N_ = 64;
constexpr int ROWS = 16;      // q rows per block
constexpr int THREADS = 256;  // 4 waves; one wave per q row, 4 rows in flight

__global__ __launch_bounds__(THREADS) void attn_fused(
    const float* __restrict__ query, const float* __restrict__ key,
    const float* __restrict__ value, const float* __restrict__ Wp,
    const float* __restrict__ bp, float* __restrict__ attended,
    float* __restrict__ weights)
{
    __shared__ f32x4 sK[L_ / 4];
    __shared__ f32x4 sV[L_ / 4];
    __shared__ float sred[8];

    const int tid  = threadIdx.x;
    const int lane = tid & 63;
    const int wave = tid >> 6;

    constexpr int BPB = L_ / ROWS;               // blocks per batch = 128
    const int b  = blockIdx.x / BPB;
    const int q0 = (blockIdx.x % BPB) * ROWS;

    const f32x4* K4 = reinterpret_cast<const f32x4*>(key + b * L_);
    const f32x4* V4 = reinterpret_cast<const f32x4*>(value + b * L_);

    // Stage K,V rows into LDS; fold in Kmax/Kmin reduction.
    float kmax = -3.4e38f, kmin = 3.4e38f;
    for (int i = tid; i < L_ / 4; i += THREADS) {
        f32x4 kk = K4[i];
        f32x4 vv = V4[i];
        sK[i] = kk;
        sV[i] = vv;
        kmax = fmaxf(kmax, fmaxf(fmaxf(kk.x, kk.y), fmaxf(kk.z, kk.w)));
        kmin = fminf(kmin, fminf(fminf(kk.x, kk.y), fminf(kk.z, kk.w)));
    }
    #pragma unroll
    for (int off = 32; off; off >>= 1) {
        kmax = fmaxf(kmax, __shfl_xor(kmax, off));
        kmin = fminf(kmin, __shfl_xor(kmin, off));
    }
    if (lane == 0) { sred[wave] = kmax; sred[4 + wave] = kmin; }

    // s2 = sum W^2, sb = sum W*b  (N=64 -> one value per lane)
    const float w_l = Wp[lane];
    const float b_l = bp[lane];
    float s2 = w_l * w_l, sb = w_l * b_l;
    #pragma unroll
    for (int off = 32; off; off >>= 1) {
        s2 += __shfl_xor(s2, off);
        sb += __shfl_xor(sb, off);
    }

    __syncthreads();
    kmax = fmaxf(fmaxf(sred[0], sred[1]), fmaxf(sred[2], sred[3]));
    kmin = fminf(fminf(sred[4], sred[5]), fminf(sred[6], sred[7]));

    const float LOG2E = 1.4426950408889634f;

    for (int r = wave; r < ROWS; r += THREADS / 64) {
        const int q = q0 + r;
        const float Q     = query[b * L_ + q];
        const float alpha = fmaf(Q, s2, sb);
        const float c1    = alpha * LOG2E;
        const float m2    = (alpha > 0.f ? alpha * kmax : alpha * kmin) * LOG2E;

        float p[32];
        float sum = 0.f, pv = 0.f;
        #pragma unroll
        for (int i = 0; i < 8; ++i) {
            f32x4 kk = sK[lane + 64 * i];
            f32x4 vv = sV[lane + 64 * i];
            float p0 = __builtin_amdgcn_exp2f(fmaf(c1, kk.x, -m2));
            float p1 = __builtin_amdgcn_exp2f(fmaf(c1, kk.y, -m2));
            float p2 = __builtin_amdgcn_exp2f(fmaf(c1, kk.z, -m2));
            float p3 = __builtin_amdgcn_exp2f(fmaf(c1, kk.w, -m2));
            p[4 * i + 0] = p0; p[4 * i + 1] = p1;
            p[4 * i + 2] = p2; p[4 * i + 3] = p3;
            sum += (p0 + p1) + (p2 + p3);
            pv  += (p0 * vv.x + p1 * vv.y) + (p2 * vv.z + p3 * vv.w);
        }
        #pragma unroll
        for (int off = 32; off; off >>= 1) {
            sum += __shfl_xor(sum, off);
            pv  += __shfl_xor(pv, off);
        }
        const float inv  = 1.0f / sum;
        const float vbar = pv * inv;

        // attended[b,q,n] = vbar*W_n + b_n  (64 floats, lane n writes n)
        attended[(size_t)(b * L_ + q) * N_ + lane] = fmaf(vbar, w_l, b_l);

        // weights[b,q,:] — 2048 normalized probs, streamed nontemporal.
        f32x4* wrow = reinterpret_cast<f32x4*>(weights + (size_t)(b * L_ + q) * L_);
        #pragma unroll
        for (int i = 0; i < 8; ++i) {
            f32x4 o;
            o.x = p[4 * i + 0] * inv;
            o.y = p[4 * i + 1] * inv;
            o.z = p[4 * i + 2] * inv;
            o.w = p[4 * i + 3] * inv;
            __builtin_nontemporal_store(o, wrow + lane + 64 * i);
        }
    }
}

extern "C" void kernel_launch(void* const* d_in, const int* in_sizes, int n_in,
                              void* d_out, int out_size, void* d_ws, size_t ws_size,
                              hipStream_t stream) {
    const float* query = (const float*)d_in[0];
    const float* key   = (const float*)d_in[1];
    const float* value = (const float*)d_in[2];
    const float* W     = (const float*)d_in[3];
    const float* bvec  = (const float*)d_in[4];

    float* attended = (float*)d_out;                               // [B,L,N]
    float* weights  = (float*)d_out + (size_t)B_ * L_ * N_;        // [B,L,L]

    dim3 grid(B_ * (L_ / ROWS));
    attn_fused<<<grid, THREADS, 0, stream>>>(query, key, value, W, bvec,
                                             attended, weights);
}